// Round 5
// baseline (93.403 us; speedup 1.0000x reference)
//
#include <hip/hip_runtime.h>
#include <hip/hip_bf16.h>
#include <hip/hip_cooperative_groups.h>

namespace cg = cooperative_groups;

#define N_DET 1024
#define N_TRK 1024
#define DD 128
#define RR 3

typedef __attribute__((ext_vector_type(8))) short short8;
typedef __attribute__((ext_vector_type(4))) float f32x4;

// ---------------------------------------------------------------------------
// One cooperative kernel, 512 blocks x 256 thr (2 blocks/CU co-resident).
// Phase 1 (== round-4 prep): block b computes det rows 2b, 2b+1:
//   objb = bf16(det@Wd + bd) -> ws, trk_nb = det@Wt + bt (f32) -> d_out tail,
//   trkb = bf16(trk) -> ws; block 0 reduces wsum/bsum.
// __threadfence + grid.sync() -> cross-XCD visibility.
// Phase 2 (== round-4 fuse, 2 tiles/block): swapped mfma(trkb, objb) -> D[m][n],
//   lane owns 4 consecutive m -> 3 aligned float4 rel loads + 1 float4 store.
// ---------------------------------------------------------------------------
__global__ __launch_bounds__(256) void fused_coop_kernel(
    const float* __restrict__ det, const float* __restrict__ trk,
    const float* __restrict__ rel,
    const float* __restrict__ Wd, const float* __restrict__ bd,
    const float* __restrict__ Wt, const float* __restrict__ bt,
    const float* __restrict__ Wr, const float* __restrict__ br,
    __hip_bfloat16* __restrict__ objb, __hip_bfloat16* __restrict__ trkb,
    float* __restrict__ out, float* __restrict__ trk_nb,
    float* __restrict__ wsum)
{
    const int tid  = threadIdx.x;
    const int col  = tid & 127;
    const int half = tid >> 7;          // k-half: 0 -> k<64, 1 -> k>=64
    const int row0 = blockIdx.x * 2;

    __shared__ float det_s[2][DD];
    __shared__ float partd[2][DD];
    __shared__ float partt[2][DD];

    // ---------------- Phase 1: prep ----------------
    det_s[half][col] = det[row0 * DD + tid];
    __syncthreads();

    float ad0 = 0.f, ad1 = 0.f, at0 = 0.f, at1 = 0.f;
    const int kbase = half * 64;
    #pragma unroll 8
    for (int k = 0; k < 64; ++k) {
        const int kk = kbase + k;
        const float wd = Wd[kk * DD + col];
        const float wt = Wt[kk * DD + col];
        const float d0 = det_s[0][kk], d1 = det_s[1][kk];
        ad0 = fmaf(d0, wd, ad0);
        ad1 = fmaf(d1, wd, ad1);
        at0 = fmaf(d0, wt, at0);
        at1 = fmaf(d1, wt, at1);
    }

    if (half == 1) {
        partd[0][col] = ad0; partd[1][col] = ad1;
        partt[0][col] = at0; partt[1][col] = at1;
    }
    __syncthreads();

    if (half == 0) {
        const float bdv = bd[col], btv = bt[col];
        objb[row0 * DD + col]         = __float2bfloat16(ad0 + partd[0][col] + bdv);
        objb[(row0 + 1) * DD + col]   = __float2bfloat16(ad1 + partd[1][col] + bdv);
        trk_nb[row0 * DD + col]       = at0 + partt[0][col] + btv;
        trk_nb[(row0 + 1) * DD + col] = at1 + partt[1][col] + btv;
    } else {
        trkb[row0 * DD + col]       = __float2bfloat16(trk[row0 * DD + col]);
        trkb[(row0 + 1) * DD + col] = __float2bfloat16(trk[(row0 + 1) * DD + col]);
    }

    if (blockIdx.x == 0 && tid < 64) {
        float v0 = Wr[tid]          + Wr[64 + tid];
        float v1 = Wr[DD + tid]     + Wr[DD + 64 + tid];
        float v2 = Wr[2 * DD + tid] + Wr[2 * DD + 64 + tid];
        float v3 = br[tid]          + br[64 + tid];
        #pragma unroll
        for (int off = 32; off > 0; off >>= 1) {
            v0 += __shfl_down(v0, off);
            v1 += __shfl_down(v1, off);
            v2 += __shfl_down(v2, off);
            v3 += __shfl_down(v3, off);
        }
        if (tid == 0) { wsum[0] = v0; wsum[1] = v1; wsum[2] = v2; wsum[3] = v3; }
    }

    // ---------------- grid-wide barrier ----------------
    __threadfence();
    cg::this_grid().sync();

    // ---------------- Phase 2: fuse (2 tiles per block) ----------------
    const int w  = tid >> 6;
    const int l  = tid & 63;
    const int lq = l >> 4;
    const int lr = l & 15;

    const float inv = 0.08838834764831845f;     // 1/sqrt(128)
    const float w0 = wsum[0] * inv, w1 = wsum[1] * inv;
    const float w2 = wsum[2] * inv, bs = wsum[3] * inv;

    #pragma unroll
    for (int ti = 0; ti < 2; ++ti) {
        const int tile   = blockIdx.x + ti * 512;    // 0..1023
        const int mchunk = tile & 15;                // 16 m-chunks of 64
        const int nblk   = tile >> 4;                // 64 n-blocks of 16
        const int m0 = mchunk * 64 + w * 16;
        const int n0 = nblk * 16;

        const short8* ap = reinterpret_cast<const short8*>(trkb + (size_t)(m0 + lr) * DD + lq * 8);
        const short8* bp = reinterpret_cast<const short8*>(objb + (size_t)(n0 + lr) * DD + lq * 8);

        f32x4 acc = {0.f, 0.f, 0.f, 0.f};
        #pragma unroll
        for (int ks = 0; ks < 4; ++ks) {
            const short8 a = ap[ks * 4];             // advance K by 32
            const short8 b = bp[ks * 4];
            acc = __builtin_amdgcn_mfma_f32_16x16x32_bf16(a, b, acc, 0, 0, 0);
        }

        const int n  = n0 + lr;
        const int mb = m0 + lq * 4;
        const float4* rp = reinterpret_cast<const float4*>(rel + ((size_t)n * N_TRK + mb) * RR);
        const float4 v0 = rp[0], v1 = rp[1], v2 = rp[2];

        float4 res;
        res.x = fmaf(acc[0], inv, bs + v0.x * w0 + v0.y * w1 + v0.z * w2);
        res.y = fmaf(acc[1], inv, bs + v0.w * w0 + v1.x * w1 + v1.y * w2);
        res.z = fmaf(acc[2], inv, bs + v1.z * w0 + v1.w * w1 + v2.x * w2);
        res.w = fmaf(acc[3], inv, bs + v2.y * w0 + v2.z * w1 + v2.w * w2);

        *reinterpret_cast<float4*>(out + (size_t)n * N_TRK + mb) = res;
    }
}

extern "C" void kernel_launch(void* const* d_in, const int* in_sizes, int n_in,
                              void* d_out, int out_size, void* d_ws, size_t ws_size,
                              hipStream_t stream) {
    const float* det = (const float*)d_in[0];
    const float* trk = (const float*)d_in[1];
    const float* rel = (const float*)d_in[2];
    const float* Wd  = (const float*)d_in[3];
    const float* bd  = (const float*)d_in[4];
    const float* Wt  = (const float*)d_in[5];
    const float* bt  = (const float*)d_in[6];
    const float* Wr  = (const float*)d_in[7];
    const float* br  = (const float*)d_in[8];

    float* out_mat = (float*)d_out;                        // [N_DET, N_TRK]
    float* out_trk = out_mat + (size_t)N_DET * N_TRK;      // [N_DET, D]

    __hip_bfloat16* objb = (__hip_bfloat16*)d_ws;          // [N_DET, D] bf16
    __hip_bfloat16* trkb = objb + (size_t)N_DET * DD;      // [N_TRK, D] bf16
    float* wsum = (float*)(trkb + (size_t)N_TRK * DD);     // [4]

    void* args[] = {
        (void*)&det, (void*)&trk, (void*)&rel,
        (void*)&Wd, (void*)&bd, (void*)&Wt, (void*)&bt, (void*)&Wr, (void*)&br,
        (void*)&objb, (void*)&trkb, (void*)&out_mat, (void*)&out_trk, (void*)&wsum
    };
    hipLaunchCooperativeKernel((void*)fused_coop_kernel,
                               dim3(512), dim3(256), args, 0, stream);
}

// Round 7
// 22.521 us; speedup vs baseline: 4.1474x; 4.1474x over previous
//
#include <hip/hip_runtime.h>
#include <hip/hip_bf16.h>

#define N_DET 1024
#define N_TRK 1024
#define DD 128
#define RR 3

typedef __attribute__((ext_vector_type(8))) short short8;
typedef __attribute__((ext_vector_type(4))) float f32x4;

static __device__ __forceinline__ short bfb(float x) {
    __hip_bfloat16 h = __float2bfloat16(x);
    return __builtin_bit_cast(short, h);
}
static __device__ __forceinline__ short8 packbf8(const float* f) {
    short8 r;
    #pragma unroll
    for (int j = 0; j < 8; ++j) r[j] = bfb(f[j]);
    return r;
}

// ---------------------------------------------------------------------------
// Kernel 1 (d2t): SELF-CONTAINED — no prep dependency.
// Grid (64 mchunks, 8 nbands) = 512 blocks x 256 thr (4 waves, 2 blocks/CU).
// Block tile: m in [mc*16, mc*16+16), n in [nb*128, nb*128+128).
//
// Phase 1: trkP[m][k] = sum_d trk[m][d] * Wd[k][d]   (= trk @ Wd^T)
//   so that sum_k trkP[m][k]*det[n][k] = trk[m] . (det[n] @ Wd)  [R6 bug fix:
//   R6 computed trk@Wd = det^T Wd^T trk — wrong transpose].
//   MFMA: A = trk rows, B[d][k_out] = Wd[k_out][d] -> lane reads CONTIGUOUS
//   8-float row segments of Wd. D[m][k] bf16 -> XOR-swizzled LDS.
//   Wave wv covers k_out chunks {2wv, 2wv+1}.
//   Wave 0 also computes bdot[m] = b_det . trk[m] (16 rows).
//
// Phase 2: A-frags = trkP rows (regs, constant across n). Wave wv handles
//   n-subtiles {2wv, 2wv+1} [R6 bug fix: was 4x redundant].
//   D[m][n] = mfma(trkP_m, det_n): lane owns n = lr fixed, m = 4 consecutive
//   -> 3 aligned float4 rel loads + 1 float4 store (R4-proven epilogue).
// ---------------------------------------------------------------------------
__global__ __launch_bounds__(256) void d2t_kernel(
    const float* __restrict__ det, const float* __restrict__ trk,
    const float* __restrict__ rel,
    const float* __restrict__ Wd, const float* __restrict__ bd,
    const float* __restrict__ Wr, const float* __restrict__ br,
    float* __restrict__ out)
{
    const int t  = threadIdx.x;
    const int l  = t & 63;
    const int hi = l >> 4;        // 0..3
    const int lr = l & 15;
    const int wv = t >> 6;        // wave 0..3
    const int m0 = blockIdx.x * 16;
    const int n0 = blockIdx.y * 128;

    __shared__ __align__(16) char trkP[16 * 256];   // [16 m][128 k] bf16, swizzled
    __shared__ __align__(16) float bdot[16];        // b_det . trk[m]

    // ---- wsum/bsum: per-wave redundant butterfly reduce ----
    float v0 = Wr[l]       + Wr[64 + l];
    float v1 = Wr[128 + l] + Wr[192 + l];
    float v2 = Wr[256 + l] + Wr[320 + l];
    float v3 = br[l]       + br[64 + l];
    #pragma unroll
    for (int off = 1; off < 64; off <<= 1) {
        v0 += __shfl_xor(v0, off);
        v1 += __shfl_xor(v1, off);
        v2 += __shfl_xor(v2, off);
        v3 += __shfl_xor(v3, off);
    }
    const float inv = 0.08838834764831845f;         // 1/sqrt(128)
    const float w0 = v0 * inv, w1 = v1 * inv, w2 = v2 * inv, bs = v3 * inv;

    // ---- bdot[m] = b_det . trk[m0+m]  (wave 0; bd==0 in bench but kept) ----
    if (wv == 0) {
        const int row  = l >> 2;    // 0..15
        const int part = l & 3;     // 0..3, 32 elems each
        const float* tp = trk + (size_t)(m0 + row) * DD + part * 32;
        const float* bp = bd + part * 32;
        float s = 0.f;
        #pragma unroll
        for (int j = 0; j < 32; ++j) s = fmaf(bp[j], tp[j], s);
        s += __shfl_xor(s, 1);
        s += __shfl_xor(s, 2);
        if (part == 0) bdot[row] = s;
    }

    // ---- Phase 1: trkP = trk[m0..m0+16) @ Wd^T ----
    short8 atrk[4];                                 // trk A-frags (row m0+lr)
    #pragma unroll
    for (int ks = 0; ks < 4; ++ks) {
        const float* p = trk + (size_t)(m0 + lr) * DD + ks * 32 + hi * 8;
        float f[8];
        *reinterpret_cast<float4*>(&f[0]) = *reinterpret_cast<const float4*>(p);
        *reinterpret_cast<float4*>(&f[4]) = *reinterpret_cast<const float4*>(p + 4);
        atrk[ks] = packbf8(f);
    }

    #pragma unroll
    for (int dcs = 0; dcs < 2; ++dcs) {
        const int dc = wv * 2 + dcs;                // k_out chunk 0..7
        f32x4 acc = {0.f, 0.f, 0.f, 0.f};
        #pragma unroll
        for (int ks = 0; ks < 4; ++ks) {
            // B[d][k_out] = Wd[k_out][d]: lane (hi,lr) reads
            // Wd[dc*16+lr][ks*32+hi*8 .. +7]  -> contiguous row segment
            const float* p = Wd + (size_t)(dc * 16 + lr) * DD + ks * 32 + hi * 8;
            float wf[8];
            *reinterpret_cast<float4*>(&wf[0]) = *reinterpret_cast<const float4*>(p);
            *reinterpret_cast<float4*>(&wf[4]) = *reinterpret_cast<const float4*>(p + 4);
            const short8 bw = packbf8(wf);
            acc = __builtin_amdgcn_mfma_f32_16x16x32_bf16(atrk[ks], bw, acc, 0, 0, 0);
        }
        // D: row m = hi*4+r, col k = dc*16+lr  -> swizzled bf16 store
        #pragma unroll
        for (int r = 0; r < 4; ++r) {
            const int m = hi * 4 + r;
            const int k = dc * 16 + lr;
            const int off = (m * 256 + k * 2) ^ ((m & 7) << 4);
            *reinterpret_cast<short*>(&trkP[off]) = bfb(acc[r]);
        }
    }
    __syncthreads();

    // ---- A2 frags: trkP row lr, held in regs for both n-iters ----
    short8 am[4];
    #pragma unroll
    for (int ks = 0; ks < 4; ++ks) {
        const int off = (lr * 256 + ks * 64 + hi * 16) ^ ((lr & 7) << 4);
        am[ks] = *reinterpret_cast<const short8*>(&trkP[off]);
    }
    const float4 bd4 = *reinterpret_cast<const float4*>(&bdot[hi * 4]);

    // ---- Phase 2: wave wv handles n-subtiles {2wv, 2wv+1} ----
    #pragma unroll
    for (int its = 0; its < 2; ++its) {
        const int nbase = n0 + (wv * 2 + its) * 16;
        f32x4 acc = {0.f, 0.f, 0.f, 0.f};
        #pragma unroll
        for (int ks = 0; ks < 4; ++ks) {
            const float* p = det + (size_t)(nbase + lr) * DD + ks * 32 + hi * 8;
            float f[8];
            *reinterpret_cast<float4*>(&f[0]) = *reinterpret_cast<const float4*>(p);
            *reinterpret_cast<float4*>(&f[4]) = *reinterpret_cast<const float4*>(p + 4);
            const short8 bn = packbf8(f);
            acc = __builtin_amdgcn_mfma_f32_16x16x32_bf16(am[ks], bn, acc, 0, 0, 0);
        }
        // lane owns n = nbase+lr, m = m0 + hi*4 .. +3
        const int n  = nbase + lr;
        const int mb = m0 + hi * 4;
        const float4* rp = reinterpret_cast<const float4*>(rel + ((size_t)n * N_TRK + mb) * RR);
        const float4 r0 = rp[0], r1 = rp[1], r2 = rp[2];
        float4 res;
        res.x = fmaf(acc[0] + bd4.x, inv, bs + r0.x * w0 + r0.y * w1 + r0.z * w2);
        res.y = fmaf(acc[1] + bd4.y, inv, bs + r0.w * w0 + r1.x * w1 + r1.y * w2);
        res.z = fmaf(acc[2] + bd4.z, inv, bs + r1.z * w0 + r1.w * w1 + r2.x * w2);
        res.w = fmaf(acc[3] + bd4.w, inv, bs + r2.y * w0 + r2.z * w1 + r2.w * w2);
        *reinterpret_cast<float4*>(out + (size_t)n * N_TRK + mb) = res;
    }
}

// ---------------------------------------------------------------------------
// Kernel 2 (aux, INDEPENDENT): trk_nb = det @ Wt + bt, exact f32.
// R4-proven structure: 512 blocks x 256 thr, 2 rows, k-split 2.
// ---------------------------------------------------------------------------
__global__ __launch_bounds__(256) void trknb_kernel(
    const float* __restrict__ det,
    const float* __restrict__ Wt, const float* __restrict__ bt,
    float* __restrict__ trk_nb)
{
    const int tid  = threadIdx.x;
    const int col  = tid & 127;
    const int half = tid >> 7;          // k-half
    const int row0 = blockIdx.x * 2;

    __shared__ float det_s[2][DD];
    __shared__ float partt[2][DD];

    det_s[half][col] = det[row0 * DD + tid];
    __syncthreads();

    float at0 = 0.f, at1 = 0.f;
    const int kbase = half * 64;
    #pragma unroll 8
    for (int k = 0; k < 64; ++k) {
        const int kk = kbase + k;
        const float wt = Wt[kk * DD + col];
        at0 = fmaf(det_s[0][kk], wt, at0);
        at1 = fmaf(det_s[1][kk], wt, at1);
    }

    if (half == 1) { partt[0][col] = at0; partt[1][col] = at1; }
    __syncthreads();

    if (half == 0) {
        const float btv = bt[col];
        trk_nb[row0 * DD + col]       = at0 + partt[0][col] + btv;
        trk_nb[(row0 + 1) * DD + col] = at1 + partt[1][col] + btv;
    }
}

extern "C" void kernel_launch(void* const* d_in, const int* in_sizes, int n_in,
                              void* d_out, int out_size, void* d_ws, size_t ws_size,
                              hipStream_t stream) {
    const float* det = (const float*)d_in[0];
    const float* trk = (const float*)d_in[1];
    const float* rel = (const float*)d_in[2];
    const float* Wd  = (const float*)d_in[3];
    const float* bd  = (const float*)d_in[4];
    const float* Wt  = (const float*)d_in[5];
    const float* bt  = (const float*)d_in[6];
    const float* Wr  = (const float*)d_in[7];
    const float* br  = (const float*)d_in[8];

    float* out_mat = (float*)d_out;                        // [N_DET, N_TRK]
    float* out_trk = out_mat + (size_t)N_DET * N_TRK;      // [N_DET, D]

    // Two INDEPENDENT nodes — no edge between them in the captured graph.
    d2t_kernel<<<dim3(64, 8), 256, 0, stream>>>(
        det, trk, rel, Wd, bd, Wr, br, out_mat);

    trknb_kernel<<<N_DET / 2, 256, 0, stream>>>(
        det, Wt, bt, out_trk);
}

// Round 8
// 16.945 us; speedup vs baseline: 5.5120x; 1.3290x over previous
//
#include <hip/hip_runtime.h>
#include <hip/hip_bf16.h>

#define N_DET 1024
#define N_TRK 1024
#define DD 128
#define RR 3

typedef __attribute__((ext_vector_type(8))) short short8;
typedef __attribute__((ext_vector_type(4))) float f32x4;

// ---------------------------------------------------------------------------
// Kernel A (prep): 256 blocks x 256 threads, 4 det rows per block, k-split 2.
//   (4 rows/block halves per-block-amortized weight traffic vs R4: 32 MB total)
//   objb    = bf16(det @ W_det + b_det)            -> ws
//   trk_nb  = det @ W_trk + b_trk (exact f32)      -> d_out tail
//   trkb    = bf16(track_embedding)                -> ws
// ---------------------------------------------------------------------------
__global__ __launch_bounds__(256) void prep_kernel(
    const float* __restrict__ det, const float* __restrict__ trk,
    const float* __restrict__ Wd, const float* __restrict__ bd,
    const float* __restrict__ Wt, const float* __restrict__ bt,
    __hip_bfloat16* __restrict__ objb, __hip_bfloat16* __restrict__ trkb,
    float* __restrict__ trk_nb)
{
    const int tid  = threadIdx.x;
    const int col  = tid & 127;
    const int half = tid >> 7;          // k-half: 0 -> k<64, 1 -> k>=64
    const int row0 = blockIdx.x * 4;

    __shared__ float det_s[4][DD];
    __shared__ float partd[4][DD];
    __shared__ float partt[4][DD];

    #pragma unroll
    for (int i = 0; i < 2; ++i) {
        const int e = tid + i * 256;
        det_s[e >> 7][e & 127] = det[row0 * DD + e];
    }
    __syncthreads();

    float ad[4] = {0.f, 0.f, 0.f, 0.f};
    float at[4] = {0.f, 0.f, 0.f, 0.f};
    const int kbase = half * 64;
    #pragma unroll 8
    for (int k = 0; k < 64; ++k) {
        const int kk = kbase + k;
        const float wd = Wd[kk * DD + col];
        const float wt = Wt[kk * DD + col];
        #pragma unroll
        for (int r = 0; r < 4; ++r) {
            ad[r] = fmaf(det_s[r][kk], wd, ad[r]);
            at[r] = fmaf(det_s[r][kk], wt, at[r]);
        }
    }

    if (half == 1) {
        #pragma unroll
        for (int r = 0; r < 4; ++r) { partd[r][col] = ad[r]; partt[r][col] = at[r]; }
    }
    __syncthreads();

    if (half == 0) {
        const float bdv = bd[col], btv = bt[col];
        #pragma unroll
        for (int r = 0; r < 4; ++r) {
            objb[(row0 + r) * DD + col]   = __float2bfloat16(ad[r] + partd[r][col] + bdv);
            trk_nb[(row0 + r) * DD + col] = at[r] + partt[r][col] + btv;
        }
    } else {
        #pragma unroll
        for (int i = 0; i < 4; ++i) {
            const int e = col + i * 128;
            trkb[row0 * DD + e] = __float2bfloat16(trk[row0 * DD + e]);
        }
    }
}

// ---------------------------------------------------------------------------
// Kernel B (fuse): SWAPPED operands — D = mfma(trkb, objb) -> D[m][n].
// Lane l: n = n0 + (l&15) fixed, m = m0 + (l>>4)*4 + {0..3} CONSECUTIVE.
//   -> rel epilogue: 3 aligned float4 loads/lane; output: 1 float4 store/lane.
// wsum/bsum: per-wave redundant __shfl_xor butterfly (R7-verified) — removes
// the global wsum round-trip and the prep dependency for it.
// Block = 4 waves (m chunks), grid (16, 64) -> 4 blocks/CU, 4 waves/SIMD.
// ---------------------------------------------------------------------------
__global__ __launch_bounds__(256) void fuse_mfma_kernel(
    const __hip_bfloat16* __restrict__ objb,
    const __hip_bfloat16* __restrict__ trkb,
    const float* __restrict__ rel,
    const float* __restrict__ Wr, const float* __restrict__ br,
    float* __restrict__ out)
{
    const int t  = threadIdx.x;
    const int w  = t >> 6;
    const int l  = t & 63;
    const int lq = l >> 4;                      // 0..3
    const int lr = l & 15;
    const int m0 = blockIdx.x * 64 + w * 16;
    const int n0 = blockIdx.y * 16;

    // ---- wsum/bsum butterfly (redundant per wave; no LDS, no global dep) ----
    float v0 = Wr[l]       + Wr[64 + l];
    float v1 = Wr[128 + l] + Wr[192 + l];
    float v2 = Wr[256 + l] + Wr[320 + l];
    float v3 = br[l]       + br[64 + l];
    #pragma unroll
    for (int off = 1; off < 64; off <<= 1) {
        v0 += __shfl_xor(v0, off);
        v1 += __shfl_xor(v1, off);
        v2 += __shfl_xor(v2, off);
        v3 += __shfl_xor(v3, off);
    }
    const float inv = 0.08838834764831845f;     // 1/sqrt(128)
    const float w0 = v0 * inv, w1 = v1 * inv, w2 = v2 * inv, bs = v3 * inv;

    // A = trkb rows (m), B = objb rows (n); 16B/lane contiguous frags.
    const short8* ap = reinterpret_cast<const short8*>(trkb + (size_t)(m0 + lr) * DD + lq * 8);
    const short8* bp = reinterpret_cast<const short8*>(objb + (size_t)(n0 + lr) * DD + lq * 8);

    f32x4 acc = {0.f, 0.f, 0.f, 0.f};
    #pragma unroll
    for (int ks = 0; ks < 4; ++ks) {
        const short8 a = ap[ks * 4];            // advance K by 32
        const short8 b = bp[ks * 4];
        acc = __builtin_amdgcn_mfma_f32_16x16x32_bf16(a, b, acc, 0, 0, 0);
    }

    // epilogue: lane owns n = n0+lr, m = m0+lq*4 .. +3
    const int n  = n0 + lr;
    const int mb = m0 + lq * 4;
    const float4* rp = reinterpret_cast<const float4*>(rel + ((size_t)n * N_TRK + mb) * RR);
    const float4 r0 = rp[0], r1 = rp[1], r2 = rp[2];

    float4 res;
    res.x = fmaf(acc[0], inv, bs + r0.x * w0 + r0.y * w1 + r0.z * w2);
    res.y = fmaf(acc[1], inv, bs + r0.w * w0 + r1.x * w1 + r1.y * w2);
    res.z = fmaf(acc[2], inv, bs + r1.z * w0 + r1.w * w1 + r2.x * w2);
    res.w = fmaf(acc[3], inv, bs + r2.y * w0 + r2.z * w1 + r2.w * w2);

    *reinterpret_cast<float4*>(out + (size_t)n * N_TRK + mb) = res;
}

extern "C" void kernel_launch(void* const* d_in, const int* in_sizes, int n_in,
                              void* d_out, int out_size, void* d_ws, size_t ws_size,
                              hipStream_t stream) {
    const float* det = (const float*)d_in[0];
    const float* trk = (const float*)d_in[1];
    const float* rel = (const float*)d_in[2];
    const float* Wd  = (const float*)d_in[3];
    const float* bd  = (const float*)d_in[4];
    const float* Wt  = (const float*)d_in[5];
    const float* bt  = (const float*)d_in[6];
    const float* Wr  = (const float*)d_in[7];
    const float* br  = (const float*)d_in[8];

    float* out_mat = (float*)d_out;                        // [N_DET, N_TRK]
    float* out_trk = out_mat + (size_t)N_DET * N_TRK;      // [N_DET, D]

    __hip_bfloat16* objb = (__hip_bfloat16*)d_ws;          // [N_DET, D] bf16
    __hip_bfloat16* trkb = objb + (size_t)N_DET * DD;      // [N_TRK, D] bf16

    prep_kernel<<<N_DET / 4, 256, 0, stream>>>(
        det, trk, Wd, bd, Wt, bt, objb, trkb, out_trk);

    fuse_mfma_kernel<<<dim3(N_TRK / 64, N_DET / 16), 256, 0, stream>>>(
        objb, trkb, rel, Wr, br, out_mat);
}